// Round 1
// baseline (430.843 us; speedup 1.0000x reference)
//
#include <hip/hip_runtime.h>
#include <cstdint>
#include <cstddef>

#define CH 128
#define BM 128

typedef __attribute__((ext_vector_type(8))) short bf16x8;
typedef __attribute__((ext_vector_type(4))) float f32x4;

__device__ __forceinline__ unsigned short f2bf(float x){
    unsigned int u = __float_as_uint(x);
    u = (u + 0x7FFFu + ((u >> 16) & 1u)) >> 16;   // RNE
    return (unsigned short)u;
}
__device__ __forceinline__ float bf2f(unsigned short b){
    return __uint_as_float(((unsigned int)b) << 16);
}

// ---------------------------------------------------------------------------
// k0: transpose+convert the 3 weight matrices to bf16 wT[mat][n][k] (n=out ch,
//     k=in ch, k contiguous for MFMA B-frag b128 reads); zero sums[256*256].
// ---------------------------------------------------------------------------
__global__ __launch_bounds__(256) void k0_prep(
        const float* __restrict__ w_self, const float* __restrict__ w_h,
        const float* __restrict__ w_t, unsigned short* __restrict__ wT,
        float* __restrict__ sums){
    int t = blockIdx.x * 256 + threadIdx.x;          // grid 256 -> 65536 threads
    if (t < 256*256) sums[t] = 0.f;
    if (t < 3*CH*CH){
        int mat = t / (CH*CH);
        int r = t - mat*(CH*CH);
        int k = r >> 7, n = r & 127;
        const float* w = (mat == 0) ? w_self : ((mat == 1) ? w_h : w_t);
        wT[mat*CH*CH + n*CH + k] = f2bf(w[k*CH + n]);
    }
}

// ---------------------------------------------------------------------------
// k1: H = x @ w_h, T = x @ w_t  (bf16 out, f32 MFMA accumulate).
//     One block = 128 node rows, 8 waves, each wave a 16-row stripe.
//     LDS: x tile bf16 (32K, XOR-swizzled) + whT (32K) + wtT (32K) = 96K.
// ---------------------------------------------------------------------------
__global__ __launch_bounds__(512) void k1_ht(
        const float* __restrict__ x, const unsigned short* __restrict__ wT,
        unsigned short* __restrict__ H, unsigned short* __restrict__ T, int N){
    __shared__ __align__(16) unsigned char smem[98304];
    const int tid = threadIdx.x;
    const int m0 = blockIdx.x * BM;
    // stage x tile -> bf16, swizzle byte ^= (row&7)<<4 to kill 16-way bank conflicts
    #pragma unroll
    for (int i = 0; i < 8; ++i){
        int g = tid + i*512;                 // 4096 groups of 4 elems
        int row = g >> 5, col4 = (g & 31) * 4;
        int rg = m0 + row; rg = rg < N ? rg : N-1;   // clamp tail (stores masked)
        float4 v = *(const float4*)(x + (size_t)rg*CH + col4);
        unsigned int lo = (unsigned int)f2bf(v.x) | ((unsigned int)f2bf(v.y) << 16);
        unsigned int hi = (unsigned int)f2bf(v.z) | ((unsigned int)f2bf(v.w) << 16);
        unsigned int b = ((unsigned int)(row*256 + col4*2)) ^ ((unsigned int)(row & 7) << 4);
        *(uint2*)(smem + b) = make_uint2(lo, hi);
    }
    // stage whT, wtT (already bf16): 16B chunks, same swizzle on row n
    #pragma unroll
    for (int m = 0; m < 2; ++m){
        const unsigned short* src = wT + (m+1)*CH*CH;
        unsigned char* dst = smem + 32768 + m*32768;
        #pragma unroll
        for (int i = 0; i < 4; ++i){
            int g = tid + i*512;             // 2048 chunks of 8 bf16
            int n = g >> 4, k8 = (g & 15) * 8;
            uint4 v = *(const uint4*)(src + n*CH + k8);
            unsigned int b = ((unsigned int)(n*256 + k8*2)) ^ ((unsigned int)(n & 7) << 4);
            *(uint4*)(dst + b) = v;
        }
    }
    __syncthreads();
    const int lane = tid & 63, wv = tid >> 6;
    const int lr = lane & 15, lg = lane >> 4;
    f32x4 accH[8], accT[8];
    #pragma unroll
    for (int n = 0; n < 8; ++n){ accH[n] = (f32x4){0.f,0.f,0.f,0.f}; accT[n] = (f32x4){0.f,0.f,0.f,0.f}; }
    #pragma unroll
    for (int kk = 0; kk < 4; ++kk){
        int arow = wv*16 + lr;
        unsigned int ab = ((unsigned int)(arow*256 + kk*64 + lg*16)) ^ ((unsigned int)(arow & 7) << 4);
        bf16x8 a = *(const bf16x8*)(smem + ab);
        #pragma unroll
        for (int n = 0; n < 8; ++n){
            int cc = n*16 + lr;
            unsigned int bb = ((unsigned int)(cc*256 + kk*64 + lg*16)) ^ ((unsigned int)(cc & 7) << 4);
            bf16x8 bh = *(const bf16x8*)(smem + 32768 + bb);
            bf16x8 bt = *(const bf16x8*)(smem + 65536 + bb);
            accH[n] = __builtin_amdgcn_mfma_f32_16x16x32_bf16(a, bh, accH[n], 0, 0, 0);
            accT[n] = __builtin_amdgcn_mfma_f32_16x16x32_bf16(a, bt, accT[n], 0, 0, 0);
        }
    }
    // C/D layout (HW-verified): col = lane&15, row = (lane>>4)*4 + reg
    #pragma unroll
    for (int n = 0; n < 8; ++n){
        int cc = n*16 + lr;
        #pragma unroll
        for (int j = 0; j < 4; ++j){
            int mr = m0 + wv*16 + lg*4 + j;
            if (mr < N){
                H[(size_t)mr*CH + cc] = f2bf(accH[n][j]);
                T[(size_t)mr*CH + cc] = f2bf(accT[n][j]);
            }
        }
    }
}

// ---------------------------------------------------------------------------
// k2: main edge pass. out0 = ea @ w_self (MFMA); v = out0*(1+0.5(h+t)) + ea;
//     write pre-BN v to d_out; per-channel sum/sumsq -> 256-slot partials.
//     One block = 128 edges. LDS: ea tile bf16 32K + wsT 32K + red 1K.
// ---------------------------------------------------------------------------
__global__ __launch_bounds__(512) void k2_main(
        const float* __restrict__ ea, const int* __restrict__ eidx,
        const unsigned short* __restrict__ wT,
        const unsigned short* __restrict__ H, const unsigned short* __restrict__ T,
        float* __restrict__ out, float* __restrict__ sums, int E){
    __shared__ __align__(16) unsigned char smem[66560];
    float* red = (float*)(smem + 65536);
    const int tid = threadIdx.x;
    const int e0 = blockIdx.x * BM;
    if (tid < 256) red[tid] = 0.f;
    // stage ea tile -> bf16 (MFMA A operand); residual re-reads f32 from L2
    #pragma unroll
    for (int i = 0; i < 8; ++i){
        int g = tid + i*512;
        int row = g >> 5, col4 = (g & 31) * 4;
        float4 v = *(const float4*)(ea + (size_t)(e0 + row)*CH + col4);
        unsigned int lo = (unsigned int)f2bf(v.x) | ((unsigned int)f2bf(v.y) << 16);
        unsigned int hi = (unsigned int)f2bf(v.z) | ((unsigned int)f2bf(v.w) << 16);
        unsigned int b = ((unsigned int)(row*256 + col4*2)) ^ ((unsigned int)(row & 7) << 4);
        *(uint2*)(smem + b) = make_uint2(lo, hi);
    }
    #pragma unroll
    for (int i = 0; i < 4; ++i){
        int g = tid + i*512;
        int n = g >> 4, k8 = (g & 15) * 8;
        uint4 v = *(const uint4*)(wT + n*CH + k8);
        unsigned int b = ((unsigned int)(n*256 + k8*2)) ^ ((unsigned int)(n & 7) << 4);
        *(uint4*)(smem + 32768 + b) = v;
    }
    __syncthreads();
    const int lane = tid & 63, wv = tid >> 6;
    const int lr = lane & 15, lg = lane >> 4;
    f32x4 acc[8];
    #pragma unroll
    for (int n = 0; n < 8; ++n) acc[n] = (f32x4){0.f,0.f,0.f,0.f};
    #pragma unroll
    for (int kk = 0; kk < 4; ++kk){
        int arow = wv*16 + lr;
        unsigned int ab = ((unsigned int)(arow*256 + kk*64 + lg*16)) ^ ((unsigned int)(arow & 7) << 4);
        bf16x8 a = *(const bf16x8*)(smem + ab);
        #pragma unroll
        for (int n = 0; n < 8; ++n){
            int cc = n*16 + lr;
            unsigned int bb = ((unsigned int)(cc*256 + kk*64 + lg*16)) ^ ((unsigned int)(cc & 7) << 4);
            bf16x8 bw = *(const bf16x8*)(smem + 32768 + bb);
            acc[n] = __builtin_amdgcn_mfma_f32_16x16x32_bf16(a, bw, acc[n], 0, 0, 0);
        }
    }
    // epilogue: gather h/t, elementwise, store pre-BN, accumulate sum/sumsq
    #pragma unroll
    for (int n = 0; n < 8; ++n){
        int cc = n*16 + lr;
        float s = 0.f, ss = 0.f;
        #pragma unroll
        for (int j = 0; j < 4; ++j){
            int ml = wv*16 + lg*4 + j;
            int e = e0 + ml;
            int ri = eidx[e], ci = eidx[E + e];
            float h = bf2f(H[(size_t)ri*CH + cc]);
            float t = bf2f(T[(size_t)ci*CH + cc]);
            float o0 = acc[n][j];
            float v = o0 * (1.f + 0.5f*(h + t)) + ea[(size_t)e*CH + cc];
            out[(size_t)e*CH + cc] = v;
            s += v; ss += v*v;
        }
        s  += __shfl_xor(s, 16);  s  += __shfl_xor(s, 32);
        ss += __shfl_xor(ss, 16); ss += __shfl_xor(ss, 32);
        if (lane < 16){
            atomicAdd(&red[cc], s);
            atomicAdd(&red[CH + cc], ss);
        }
    }
    __syncthreads();
    if (tid < 256) atomicAdd(&sums[(blockIdx.x & 255)*256 + tid], red[tid]);
}

// ---------------------------------------------------------------------------
// k3: reduce 256 slots -> per-channel scale/shift for fused BN+ReLU
// ---------------------------------------------------------------------------
__global__ __launch_bounds__(128) void k3_stats(
        const float* __restrict__ sums, const float* __restrict__ gamma,
        const float* __restrict__ beta, float* __restrict__ sb, float invE){
    int c = threadIdx.x;
    float s = 0.f, ss = 0.f;
    for (int i = 0; i < 256; ++i){ s += sums[i*256 + c]; ss += sums[i*256 + CH + c]; }
    float mean = s * invE;
    float var = ss * invE - mean*mean;   // biased variance (matches reference)
    float inv = rsqrtf(var + 1e-5f);
    float sc = gamma[c] * inv;
    sb[c] = sc;
    sb[CH + c] = beta[c] - mean * sc;
}

// ---------------------------------------------------------------------------
// k4: out = relu(out*scale[c] + shift[c]) in-place, float4 grid-stride
// ---------------------------------------------------------------------------
__global__ __launch_bounds__(256) void k4_norm(
        float* __restrict__ out, const float* __restrict__ sb, int n4){
    int i = blockIdx.x * 256 + threadIdx.x;
    int stride = gridDim.x * 256;
    float4* o4 = (float4*)out;
    const float4* s4 = (const float4*)sb;
    for (; i < n4; i += stride){
        float4 v = o4[i];
        int c4 = i & 31;                 // (i*4) % 128 / 4
        float4 sc = s4[c4], bi = s4[32 + c4];
        v.x = fmaxf(fmaf(v.x, sc.x, bi.x), 0.f);
        v.y = fmaxf(fmaf(v.y, sc.y, bi.y), 0.f);
        v.z = fmaxf(fmaf(v.z, sc.z, bi.z), 0.f);
        v.w = fmaxf(fmaf(v.w, sc.w, bi.w), 0.f);
        o4[i] = v;
    }
}

extern "C" void kernel_launch(void* const* d_in, const int* in_sizes, int n_in,
                              void* d_out, int out_size, void* d_ws, size_t ws_size,
                              hipStream_t stream) {
    const float* x      = (const float*)d_in[0];
    const int*   eidx   = (const int*)d_in[1];     // [2][E] (harness delivers int32)
    const float* ea     = (const float*)d_in[2];
    // d_in[3] = edge_type, unused by the reference forward
    const float* w_self = (const float*)d_in[4];
    const float* w_h    = (const float*)d_in[5];
    const float* w_t    = (const float*)d_in[6];
    const float* gamma  = (const float*)d_in[7];
    const float* beta   = (const float*)d_in[8];
    float* out = (float*)d_out;

    const int N = in_sizes[0] / CH;     // 40000
    const int E = in_sizes[3];          // 640000 (edge_type count); E % 128 == 0

    // workspace carve-up (all 16B-aligned):
    //   sums   : 256 slots * 256 f32          = 262144 B
    //   sb     : 256 f32 (scale|shift)        =   1024 B
    //   wT     : 3 * 128*128 bf16 (transposed)=  98304 B
    //   H, T   : N*128 bf16 each              = 2*10.24 MB
    float* sums = (float*)d_ws;
    float* sb   = sums + 256*256;
    unsigned short* wT = (unsigned short*)(sb + 256);
    unsigned short* H  = wT + 3*CH*CH;
    unsigned short* T  = H + (size_t)N*CH;

    k0_prep<<<256, 256, 0, stream>>>(w_self, w_h, w_t, wT, sums);
    k1_ht  <<<(N + BM - 1)/BM, 512, 0, stream>>>(x, wT, H, T, N);
    k2_main<<<E/BM, 512, 0, stream>>>(ea, eidx, wT, H, T, out, sums, E);
    k3_stats<<<1, 128, 0, stream>>>(sums, gamma, beta, sb, 1.0f/(float)E);
    k4_norm<<<2048, 256, 0, stream>>>(out, sb, E*CH/4);
}

// Round 2
// 421.653 us; speedup vs baseline: 1.0218x; 1.0218x over previous
//
#include <hip/hip_runtime.h>
#include <cstdint>
#include <cstddef>

#define CH 128
#define BM 128

typedef __attribute__((ext_vector_type(8))) short bf16x8;
typedef __attribute__((ext_vector_type(4))) float f32x4;

__device__ __forceinline__ unsigned short f2bf(float x){
    unsigned int u = __float_as_uint(x);
    u = (u + 0x7FFFu + ((u >> 16) & 1u)) >> 16;   // RNE
    return (unsigned short)u;
}
__device__ __forceinline__ float bf2f(unsigned short b){
    return __uint_as_float(((unsigned int)b) << 16);
}

// ---------------------------------------------------------------------------
// k0: transpose+convert weights to bf16 wT[mat][n][k]; zero sums[256*256].
// ---------------------------------------------------------------------------
__global__ __launch_bounds__(256) void k0_prep(
        const float* __restrict__ w_self, const float* __restrict__ w_h,
        const float* __restrict__ w_t, unsigned short* __restrict__ wT,
        float* __restrict__ sums){
    int t = blockIdx.x * 256 + threadIdx.x;
    if (t < 256*256) sums[t] = 0.f;
    if (t < 3*CH*CH){
        int mat = t / (CH*CH);
        int r = t - mat*(CH*CH);
        int k = r >> 7, n = r & 127;
        const float* w = (mat == 0) ? w_self : ((mat == 1) ? w_h : w_t);
        wT[mat*CH*CH + n*CH + k] = f2bf(w[k*CH + n]);
    }
}

// ---------------------------------------------------------------------------
// k1: H = x @ w_h, T = x @ w_t  (bf16 out, f32 MFMA accumulate). Unchanged.
// ---------------------------------------------------------------------------
__global__ __launch_bounds__(512) void k1_ht(
        const float* __restrict__ x, const unsigned short* __restrict__ wT,
        unsigned short* __restrict__ H, unsigned short* __restrict__ T, int N){
    __shared__ __align__(16) unsigned char smem[98304];
    const int tid = threadIdx.x;
    const int m0 = blockIdx.x * BM;
    #pragma unroll
    for (int i = 0; i < 8; ++i){
        int g = tid + i*512;
        int row = g >> 5, col4 = (g & 31) * 4;
        int rg = m0 + row; rg = rg < N ? rg : N-1;
        float4 v = *(const float4*)(x + (size_t)rg*CH + col4);
        unsigned int lo = (unsigned int)f2bf(v.x) | ((unsigned int)f2bf(v.y) << 16);
        unsigned int hi = (unsigned int)f2bf(v.z) | ((unsigned int)f2bf(v.w) << 16);
        unsigned int b = ((unsigned int)(row*256 + col4*2)) ^ ((unsigned int)(row & 7) << 4);
        *(uint2*)(smem + b) = make_uint2(lo, hi);
    }
    #pragma unroll
    for (int m = 0; m < 2; ++m){
        const unsigned short* src = wT + (m+1)*CH*CH;
        unsigned char* dst = smem + 32768 + m*32768;
        #pragma unroll
        for (int i = 0; i < 4; ++i){
            int g = tid + i*512;
            int n = g >> 4, k8 = (g & 15) * 8;
            uint4 v = *(const uint4*)(src + n*CH + k8);
            unsigned int b = ((unsigned int)(n*256 + k8*2)) ^ ((unsigned int)(n & 7) << 4);
            *(uint4*)(dst + b) = v;
        }
    }
    __syncthreads();
    const int lane = tid & 63, wv = tid >> 6;
    const int lr = lane & 15, lg = lane >> 4;
    f32x4 accH[8], accT[8];
    #pragma unroll
    for (int n = 0; n < 8; ++n){ accH[n] = (f32x4){0.f,0.f,0.f,0.f}; accT[n] = (f32x4){0.f,0.f,0.f,0.f}; }
    #pragma unroll
    for (int kk = 0; kk < 4; ++kk){
        int arow = wv*16 + lr;
        unsigned int ab = ((unsigned int)(arow*256 + kk*64 + lg*16)) ^ ((unsigned int)(arow & 7) << 4);
        bf16x8 a = *(const bf16x8*)(smem + ab);
        #pragma unroll
        for (int n = 0; n < 8; ++n){
            int cc = n*16 + lr;
            unsigned int bb = ((unsigned int)(cc*256 + kk*64 + lg*16)) ^ ((unsigned int)(cc & 7) << 4);
            bf16x8 bh = *(const bf16x8*)(smem + 32768 + bb);
            bf16x8 bt = *(const bf16x8*)(smem + 65536 + bb);
            accH[n] = __builtin_amdgcn_mfma_f32_16x16x32_bf16(a, bh, accH[n], 0, 0, 0);
            accT[n] = __builtin_amdgcn_mfma_f32_16x16x32_bf16(a, bt, accT[n], 0, 0, 0);
        }
    }
    #pragma unroll
    for (int n = 0; n < 8; ++n){
        int cc = n*16 + lr;
        #pragma unroll
        for (int j = 0; j < 4; ++j){
            int mr = m0 + wv*16 + lg*4 + j;
            if (mr < N){
                H[(size_t)mr*CH + cc] = f2bf(accH[n][j]);
                T[(size_t)mr*CH + cc] = f2bf(accT[n][j]);
            }
        }
    }
}

// ---------------------------------------------------------------------------
// k2 v2: latency-hidden main pass.
//   issue ea loads -> issue eidx -> issue coalesced H/T row gathers (regs)
//   -> stage ea bf16 to LDS -> MFMA -> read residual from LDS A-tile
//   -> overwrite A/B LDS with gathered H/T (octet-swizzled) -> epilogue.
// ---------------------------------------------------------------------------
__global__ __launch_bounds__(512, 4) void k2_main(
        const float* __restrict__ ea, const int* __restrict__ eidx,
        const unsigned short* __restrict__ wT,
        const unsigned short* __restrict__ H, const unsigned short* __restrict__ T,
        float* __restrict__ outf, unsigned short* __restrict__ outb,
        float* __restrict__ sums, int E){
    __shared__ __align__(16) unsigned char smem[66560];
    float* red = (float*)(smem + 65536);
    const int tid = threadIdx.x;
    const int e0 = blockIdx.x * BM;
    if (tid < 256) red[tid] = 0.f;

    // ---- issue streaming ea loads first (oldest in vmcnt queue) ----
    float4 eav[8];
    #pragma unroll
    for (int i = 0; i < 8; ++i){
        int g = tid + i*512;
        int row = g >> 5, col4 = (g & 31)*4;
        eav[i] = *(const float4*)(ea + (size_t)(e0+row)*CH + col4);
    }
    // ---- weight tile loads (L2-hot) ----
    uint4 wv4[4];
    #pragma unroll
    for (int i = 0; i < 4; ++i){
        int g = tid + i*512;
        int n = g >> 4, k8 = (g & 15)*8;
        wv4[i] = *(const uint4*)(wT + n*CH + k8);
    }
    // ---- edge indices, then coalesced 256B-row gathers of H/T ----
    int ri4[4], ci4[4];
    #pragma unroll
    for (int i = 0; i < 4; ++i){
        int r = (tid + i*512) >> 4;
        ri4[i] = eidx[e0 + r];
        ci4[i] = eidx[E + e0 + r];
    }
    uint4 hv[4], tv[4];
    #pragma unroll
    for (int i = 0; i < 4; ++i){
        int c = (tid + i*512) & 15;
        hv[i] = *(const uint4*)(H + (size_t)ri4[i]*CH + c*8);
        tv[i] = *(const uint4*)(T + (size_t)ci4[i]*CH + c*8);
    }
    // ---- stage ea -> bf16 LDS (A region, row-swizzle <<4) ----
    #pragma unroll
    for (int i = 0; i < 8; ++i){
        int g = tid + i*512;
        int row = g >> 5, col4 = (g & 31)*4;
        float4 v = eav[i];
        unsigned int lo = (unsigned int)f2bf(v.x) | ((unsigned int)f2bf(v.y) << 16);
        unsigned int hi = (unsigned int)f2bf(v.z) | ((unsigned int)f2bf(v.w) << 16);
        unsigned int b = ((unsigned int)(row*256 + col4*2)) ^ ((unsigned int)(row & 7) << 4);
        *(uint2*)(smem + b) = make_uint2(lo, hi);
    }
    // ---- stage weights -> LDS (B region) ----
    #pragma unroll
    for (int i = 0; i < 4; ++i){
        int g = tid + i*512;
        int n = g >> 4, k8 = (g & 15)*8;
        unsigned int b = ((unsigned int)(n*256 + k8*2)) ^ ((unsigned int)(n & 7) << 4);
        *(uint4*)(smem + 32768 + b) = wv4[i];
    }
    __syncthreads();

    const int lane = tid & 63, wv = tid >> 6;
    const int lr = lane & 15, lg = lane >> 4;
    f32x4 acc[8];
    #pragma unroll
    for (int n = 0; n < 8; ++n) acc[n] = (f32x4){0.f,0.f,0.f,0.f};
    #pragma unroll
    for (int kk = 0; kk < 4; ++kk){
        int arow = wv*16 + lr;
        unsigned int ab = ((unsigned int)(arow*256 + kk*64 + lg*16)) ^ ((unsigned int)(arow & 7) << 4);
        bf16x8 a = *(const bf16x8*)(smem + ab);
        #pragma unroll
        for (int n = 0; n < 8; ++n){
            int cc = n*16 + lr;
            unsigned int bb = ((unsigned int)(cc*256 + kk*64 + lg*16)) ^ ((unsigned int)(cc & 7) << 4);
            bf16x8 bw = *(const bf16x8*)(smem + 32768 + bb);
            acc[n] = __builtin_amdgcn_mfma_f32_16x16x32_bf16(a, bw, acc[n], 0, 0, 0);
        }
    }
    // ---- residual: read staged ea (bf16) before overwrite ----
    float res[32];
    #pragma unroll
    for (int n = 0; n < 8; ++n){
        int cc = n*16 + lr;
        #pragma unroll
        for (int j = 0; j < 4; ++j){
            int ml = wv*16 + lg*4 + j;
            unsigned int b = ((unsigned int)(ml*256 + cc*2)) ^ ((unsigned int)(ml & 7) << 4);
            res[n*4 + j] = bf2f(*(const unsigned short*)(smem + b));
        }
    }
    __syncthreads();   // all waves done with A/B LDS
    // ---- write gathered H/T rows into LDS (octet swizzle on addr bits 6:5) ----
    #pragma unroll
    for (int i = 0; i < 4; ++i){
        int g = tid + i*512;
        int r = g >> 4, c = g & 15;
        unsigned int b = ((unsigned int)(r*256 + c*16)) ^ ((unsigned int)((r >> 2) & 3) << 5);
        *(uint4*)(smem + b) = hv[i];
        *(uint4*)(smem + 32768 + b) = tv[i];
    }
    __syncthreads();
    // ---- epilogue ----
    #pragma unroll
    for (int n = 0; n < 8; ++n){
        int cc = n*16 + lr;
        float s = 0.f, ss = 0.f;
        #pragma unroll
        for (int j = 0; j < 4; ++j){
            int ml = wv*16 + lg*4 + j;
            unsigned int b = ((unsigned int)(ml*256 + cc*2)) ^ ((unsigned int)((ml >> 2) & 3) << 5);
            float h = bf2f(*(const unsigned short*)(smem + b));
            float t = bf2f(*(const unsigned short*)(smem + 32768 + b));
            float v = acc[n][j] * (1.f + 0.5f*(h + t)) + res[n*4 + j];
            size_t oidx = (size_t)(e0 + ml)*CH + cc;
            if (outb) outb[oidx] = f2bf(v);
            else      outf[oidx] = v;
            s += v; ss += v*v;
        }
        s  += __shfl_xor(s, 16);  s  += __shfl_xor(s, 32);
        ss += __shfl_xor(ss, 16); ss += __shfl_xor(ss, 32);
        if (lane < 16){
            atomicAdd(&red[cc], s);
            atomicAdd(&red[CH + cc], ss);
        }
    }
    __syncthreads();
    if (tid < 256) atomicAdd(&sums[(blockIdx.x & 255)*256 + tid], red[tid]);
}

// ---------------------------------------------------------------------------
// k3: reduce 256 slots -> per-channel scale/shift
// ---------------------------------------------------------------------------
__global__ __launch_bounds__(128) void k3_stats(
        const float* __restrict__ sums, const float* __restrict__ gamma,
        const float* __restrict__ beta, float* __restrict__ sb, float invE){
    int c = threadIdx.x;
    float s = 0.f, ss = 0.f;
    for (int i = 0; i < 256; ++i){ s += sums[i*256 + c]; ss += sums[i*256 + CH + c]; }
    float mean = s * invE;
    float var = ss * invE - mean*mean;
    float inv = rsqrtf(var + 1e-5f);
    float sc = gamma[c] * inv;
    sb[c] = sc;
    sb[CH + c] = beta[c] - mean * sc;
}

// ---------------------------------------------------------------------------
// k4_bf16: out_f32 = relu(bf16_v*scale + shift); 8 elems/thread
// ---------------------------------------------------------------------------
__global__ __launch_bounds__(256) void k4_bf16(
        const unsigned short* __restrict__ vb, const float* __restrict__ sb,
        float* __restrict__ out, int n8){
    int i = blockIdx.x * 256 + threadIdx.x;
    int stride = gridDim.x * 256;
    const uint4* v8 = (const uint4*)vb;
    for (; i < n8; i += stride){
        uint4 v = v8[i];
        int c8 = (i & 15) * 8;
        float4 sc0 = *(const float4*)(sb + c8);
        float4 sc1 = *(const float4*)(sb + c8 + 4);
        float4 sh0 = *(const float4*)(sb + CH + c8);
        float4 sh1 = *(const float4*)(sb + CH + c8 + 4);
        float4 o0, o1;
        o0.x = fmaxf(fmaf(bf2f((unsigned short)(v.x & 0xffff)), sc0.x, sh0.x), 0.f);
        o0.y = fmaxf(fmaf(bf2f((unsigned short)(v.x >> 16)),    sc0.y, sh0.y), 0.f);
        o0.z = fmaxf(fmaf(bf2f((unsigned short)(v.y & 0xffff)), sc0.z, sh0.z), 0.f);
        o0.w = fmaxf(fmaf(bf2f((unsigned short)(v.y >> 16)),    sc0.w, sh0.w), 0.f);
        o1.x = fmaxf(fmaf(bf2f((unsigned short)(v.z & 0xffff)), sc1.x, sh1.x), 0.f);
        o1.y = fmaxf(fmaf(bf2f((unsigned short)(v.z >> 16)),    sc1.y, sh1.y), 0.f);
        o1.z = fmaxf(fmaf(bf2f((unsigned short)(v.w & 0xffff)), sc1.z, sh1.z), 0.f);
        o1.w = fmaxf(fmaf(bf2f((unsigned short)(v.w >> 16)),    sc1.w, sh1.w), 0.f);
        *(float4*)(out + (size_t)i*8)     = o0;
        *(float4*)(out + (size_t)i*8 + 4) = o1;
    }
}

// ---------------------------------------------------------------------------
// k4_f32: fallback, in-place normalize of f32 pre-BN
// ---------------------------------------------------------------------------
__global__ __launch_bounds__(256) void k4_f32(
        float* __restrict__ out, const float* __restrict__ sb, int n4){
    int i = blockIdx.x * 256 + threadIdx.x;
    int stride = gridDim.x * 256;
    float4* o4 = (float4*)out;
    const float4* s4 = (const float4*)sb;
    for (; i < n4; i += stride){
        float4 v = o4[i];
        int c4 = i & 31;
        float4 sc = s4[c4], bi = s4[32 + c4];
        v.x = fmaxf(fmaf(v.x, sc.x, bi.x), 0.f);
        v.y = fmaxf(fmaf(v.y, sc.y, bi.y), 0.f);
        v.z = fmaxf(fmaf(v.z, sc.z, bi.z), 0.f);
        v.w = fmaxf(fmaf(v.w, sc.w, bi.w), 0.f);
        o4[i] = v;
    }
}

extern "C" void kernel_launch(void* const* d_in, const int* in_sizes, int n_in,
                              void* d_out, int out_size, void* d_ws, size_t ws_size,
                              hipStream_t stream) {
    const float* x      = (const float*)d_in[0];
    const int*   eidx   = (const int*)d_in[1];
    const float* ea     = (const float*)d_in[2];
    const float* w_self = (const float*)d_in[4];
    const float* w_h    = (const float*)d_in[5];
    const float* w_t    = (const float*)d_in[6];
    const float* gamma  = (const float*)d_in[7];
    const float* beta   = (const float*)d_in[8];
    float* out = (float*)d_out;

    const int N = in_sizes[0] / CH;     // 40000
    const int E = in_sizes[3];          // 640000

    // workspace carve-up (16B-aligned):
    float* sums = (float*)d_ws;                          // 256*256 f32
    float* sb   = sums + 256*256;                        // 256 f32
    unsigned short* wT = (unsigned short*)(sb + 256);    // 3*128*128 bf16
    unsigned short* H  = wT + 3*CH*CH;                   // N*128 bf16
    unsigned short* T  = H + (size_t)N*CH;               // N*128 bf16
    unsigned short* vb = T + (size_t)N*CH;               // E*128 bf16 (pre-BN)

    size_t base_ws  = (size_t)(256*256 + 256)*4 + (size_t)3*CH*CH*2 + 2*(size_t)N*CH*2;
    size_t need_bf  = base_ws + (size_t)E*CH*2;
    bool use_bf16   = (ws_size >= need_bf);

    k0_prep<<<256, 256, 0, stream>>>(w_self, w_h, w_t, wT, sums);
    k1_ht  <<<(N + BM - 1)/BM, 512, 0, stream>>>(x, wT, H, T, N);
    k2_main<<<E/BM, 512, 0, stream>>>(ea, eidx, wT, H, T,
                                      use_bf16 ? nullptr : out,
                                      use_bf16 ? vb : nullptr,
                                      sums, E);
    k3_stats<<<1, 128, 0, stream>>>(sums, gamma, beta, sb, 1.0f/(float)E);
    if (use_bf16)
        k4_bf16<<<2048, 256, 0, stream>>>(vb, sb, out, E*CH/8);
    else
        k4_f32<<<2048, 256, 0, stream>>>(out, sb, E*CH/4);
}